// Round 7
// baseline (137.888 us; speedup 1.0000x reference)
//
#include <hip/hip_runtime.h>
#include <stdint.h>

// ---------------------------------------------------------------------------
// MultiHeadAttention: B=1, S=4096, H=1024, NH=16, DH=64
//   q = relu(Q @ Wq^T + bq), k = ..., v = ...
//   per head: softmax(q k^T / 8) v,   output scrambled (torch-faithful
//   transpose(0,1,3,2).reshape) + queries.
// R7: attn software-pipelined (T15): QK^T(i+1) MFMA overlaps exp/pack(S(i))
//     VALU. K staged two tiles ahead, V one ahead (same 2+2 buffers, 32KB).
//     S carried across iterations in registers. Rest unchanged from R6.
// ---------------------------------------------------------------------------

#define SEQ 4096
#define HID 1024
#define NHEAD 16
#define DHEAD 64

typedef __attribute__((ext_vector_type(8))) short short8_t;     // 8 x bf16
typedef __attribute__((ext_vector_type(4))) float f32x4;        // 16x16 acc
typedef __attribute__((ext_vector_type(16))) float f32x16;      // 32x32 acc
typedef __attribute__((ext_vector_type(2))) unsigned int u32x2;

// ws layout (bf16 elements)
#define WS_QB   0u          // queries bf16 [4096][1024]
#define WS_KB   4194304u
#define WS_VB   8388608u
#define WS_WQ   12582912u   // weights bf16 [1024][1024] x3
#define WS_QO   15728640u   // q proj [4096][1024]
#define WS_KO   19922944u   // k proj (pre-scaled by (1/8)*log2e) [4096][1024]
#define WS_VT   24117248u   // v proj transposed [16][64][4096]

__device__ __forceinline__ unsigned short f2bf(float f) {
  union { float f; unsigned int u; } x; x.f = f;
  unsigned int u = x.u;
  return (unsigned short)((u + 0x7FFFu + ((u >> 16) & 1u)) >> 16);
}

// raw v_exp_f32 — valid: inputs are >= 0 (ReLU'd Q,K dot) and < ~16
__device__ __forceinline__ float fexp2(float x) {
#if __has_builtin(__builtin_amdgcn_exp2f)
  return __builtin_amdgcn_exp2f(x);
#else
  float r; asm("v_exp_f32 %0, %1" : "=v"(r) : "v"(x)); return r;
#endif
}

// packed f32x2 -> bf16x2 (lo = a, hi = b)
__device__ __forceinline__ unsigned int pk2(float a, float b) {
  unsigned int r;
  asm("v_cvt_pk_bf16_f32 %0, %1, %2" : "=v"(r) : "v"(a), "v"(b));
  return r;
}

// swap hi-32-lanes of a with lo-32-lanes of b
__device__ __forceinline__ void pl32swap(unsigned int& a, unsigned int& b) {
  asm("v_permlane32_swap_b32 %0, %1" : "+v"(a), "+v"(b));
}

__device__ __forceinline__ void gll16(const void* g, void* l) {
  __builtin_amdgcn_global_load_lds(
      (const __attribute__((address_space(1))) void*)g,
      (__attribute__((address_space(3))) void*)l, 16, 0, 0);
}

// P pack+redistribute: acs (S^T regs=t, lane=s col) -> two PV A-frags
__device__ __forceinline__ void packP(const f32x16& a, short8_t& p0,
                                      short8_t& p1) {
  unsigned int w0 = pk2(a[0], a[1]),   w1 = pk2(a[2], a[3]);
  unsigned int w2 = pk2(a[4], a[5]),   w3 = pk2(a[6], a[7]);
  unsigned int w4 = pk2(a[8], a[9]),   w5 = pk2(a[10], a[11]);
  unsigned int w6 = pk2(a[12], a[13]), w7 = pk2(a[14], a[15]);
  pl32swap(w0, w2);
  pl32swap(w1, w3);
  pl32swap(w4, w6);
  pl32swap(w5, w7);
  union { unsigned int u[4]; short8_t v; } q0, q1;
  q0.u[0] = w0; q0.u[1] = w1; q0.u[2] = w2; q0.u[3] = w3;
  q1.u[0] = w4; q1.u[1] = w5; q1.u[2] = w6; q1.u[3] = w7;
  p0 = q0.v; p1 = q1.v;
}

#define MFMA32(a, b, c) __builtin_amdgcn_mfma_f32_32x32x16_bf16(a, b, c, 0, 0, 0)

// ---------------------------------------------------------------------------
// Kernel 1: fp32 -> bf16 for 3 inputs (4M each) + 3 weights (1M each)
// ---------------------------------------------------------------------------
__global__ void __launch_bounds__(256) prep_convert(
    const float* __restrict__ qin, const float* __restrict__ kin,
    const float* __restrict__ vin, const float* __restrict__ wq,
    const float* __restrict__ wk, const float* __restrict__ wv,
    unsigned short* __restrict__ ws) {
  const int total = 3932160;  // (3*4194304 + 3*1048576) / 4
  for (int i = blockIdx.x * blockDim.x + threadIdx.x; i < total;
       i += gridDim.x * blockDim.x) {
    const float* src; unsigned short* dst; int off;
    if (i < 3145728) {
      int which = i >> 20;
      off = (i & 1048575) << 2;
      src = which == 0 ? qin : (which == 1 ? kin : vin);
      dst = ws + which * 4194304u;
    } else {
      int j = i - 3145728;
      int which = j >> 18;
      off = (j & 262143) << 2;
      src = which == 0 ? wq : (which == 1 ? wk : wv);
      dst = ws + WS_WQ + which * 1048576u;
    }
    float4 f = *(const float4*)(src + off);
    u32x2 p;
    p.x = f2bf(f.x) | ((unsigned int)f2bf(f.y) << 16);
    p.y = f2bf(f.z) | ((unsigned int)f2bf(f.w) << 16);
    *(u32x2*)(dst + off) = p;
  }
}

// ---------------------------------------------------------------------------
// Kernel 2: bf16 GEMM  C[4096,1024] = relu(X @ W^T + b), z selects Q/K/V.
// z==1 (K) output pre-scaled by (1/8)*log2e; z==2 writes vt[nh][d][t].
// XCD-aware block swizzle: each XCD takes 4 bm rows x all 8 bn.
// ---------------------------------------------------------------------------
__global__ void __launch_bounds__(256) qkv_gemm(
    unsigned short* __restrict__ ws, const float* __restrict__ bq,
    const float* __restrict__ bk, const float* __restrict__ bv) {
  __shared__ alignas(16) unsigned short lA[128 * 32];
  __shared__ alignas(16) unsigned short lB[128 * 32];
  const int z = blockIdx.z;
  const unsigned short* A = ws + z * 4194304u;
  const unsigned short* W = ws + WS_WQ + z * 1048576u;
  const float* bias = z == 0 ? bq : (z == 1 ? bk : bv);
  const int tid = threadIdx.x;
  const int lane = tid & 63;
  const int wid = tid >> 6;
  const int wr = wid >> 1, wc = wid & 1;
  const int lin = blockIdx.y * 8 + blockIdx.x;         // 0..255
  const int nid = (lin & 7) * 32 + (lin >> 3);
  const int bm = nid >> 3, bn = nid & 7;
  const int l15 = lane & 15, l4 = lane >> 4;

  f32x4 acc[4][4];
#pragma unroll
  for (int m = 0; m < 4; ++m)
#pragma unroll
    for (int n = 0; n < 4; ++n) acc[m][n] = {0.f, 0.f, 0.f, 0.f};

  const int srow = lane >> 2;
  const int scs = lane & 3;

  for (int kt = 0; kt < 1024; kt += 32) {
    __syncthreads();
#pragma unroll
    for (int c = 0; c < 2; ++c) {
      const int row = c * 64 + wid * 16 + srow;
      const int ch = scs ^ ((row >> 1) & 3);
      gll16(A + (size_t)(bm * 128 + row) * 1024 + kt + ch * 8,
            (char*)lA + c * 4096 + wid * 1024);
      gll16(W + (size_t)(bn * 128 + row) * 1024 + kt + ch * 8,
            (char*)lB + c * 4096 + wid * 1024);
    }
    __syncthreads();
    short8_t af[4], bf[4];
#pragma unroll
    for (int m = 0; m < 4; ++m) {
      const int row = wr * 64 + m * 16 + l15;
      const int ch = l4 ^ ((row >> 1) & 3);
      af[m] = *(const short8_t*)(lA + row * 32 + ch * 8);
    }
#pragma unroll
    for (int n = 0; n < 4; ++n) {
      const int row = wc * 64 + n * 16 + l15;
      const int ch = l4 ^ ((row >> 1) & 3);
      bf[n] = *(const short8_t*)(lB + row * 32 + ch * 8);
    }
#pragma unroll
    for (int m = 0; m < 4; ++m)
#pragma unroll
      for (int n = 0; n < 4; ++n)
        acc[m][n] = __builtin_amdgcn_mfma_f32_16x16x32_bf16(af[m], bf[n],
                                                            acc[m][n], 0, 0, 0);
  }

  const int row0 = bm * 128 + wr * 64;
  const int col0 = bn * 128 + wc * 64;
  if (z < 2) {
    const float scl = (z == 1) ? 0.18033688011112042f : 1.0f;  // (1/8)*log2e
    unsigned short* o = ws + WS_QO + z * 4194304u;
#pragma unroll
    for (int n = 0; n < 4; ++n) {
      const int col = col0 + n * 16 + l15;
      const float bb = bias[col];
#pragma unroll
      for (int m = 0; m < 4; ++m)
#pragma unroll
        for (int j = 0; j < 4; ++j) {
          const int row = row0 + m * 16 + l4 * 4 + j;
          o[(size_t)row * 1024 + col] = f2bf(fmaxf(acc[m][n][j] + bb, 0.f) * scl);
        }
    }
  } else {
    unsigned short* vt = ws + WS_VT;
#pragma unroll
    for (int n = 0; n < 4; ++n) {
      const int col = col0 + n * 16 + l15;
      const float bb = bias[col];
      const int nh = col >> 6, d = col & 63;
#pragma unroll
      for (int m = 0; m < 4; ++m) {
        const int t0 = row0 + m * 16 + l4 * 4;
        u32x2 p;
        p.x = f2bf(fmaxf(acc[m][n][0] + bb, 0.f)) |
              ((unsigned int)f2bf(fmaxf(acc[m][n][1] + bb, 0.f)) << 16);
        p.y = f2bf(fmaxf(acc[m][n][2] + bb, 0.f)) |
              ((unsigned int)f2bf(fmaxf(acc[m][n][3] + bb, 0.f)) << 16);
        *(u32x2*)(vt + (size_t)nh * 262144 + (size_t)d * 4096 + t0) = p;
      }
    }
  }
}

// ---------------------------------------------------------------------------
// Kernel 3: flash attention, 32x32x16 MFMA, software-pipelined.
// Block = 1 head x 128 q, 4 waves = (qg 0/1) x (tw 0/1).
// Per iter i: stage K(i+2),V(i+1); QK^T(i+1) MFMA || exp/pack(S(i)) VALU;
// PV(i); barrier. S carried in regs across iterations.
// ---------------------------------------------------------------------------
__global__ void __launch_bounds__(256, 2) attn_fwd(
    const unsigned short* __restrict__ ws, const float* __restrict__ qin,
    float* __restrict__ out) {
  // main: lK[2][64*64] 0..16KB, lV[2][64*64] 16..32KB
  // epilogue: fO[2][64][65] f32 0..33280B, fRs[2][64] 33280..33792B
  __shared__ alignas(16) char smem[33792];
  unsigned short* lKb = (unsigned short*)smem;
  unsigned short* lVb = (unsigned short*)(smem + 16384);
  float* fO = (float*)smem;
  float* fRs = (float*)(smem + 33280);

  const unsigned short* qo = ws + WS_QO;
  const char* koB = (const char*)(ws + WS_KO);
  const char* vtB = (const char*)(ws + WS_VT);
  const int nh = blockIdx.y;
  const int qb0 = blockIdx.x * 128;
  const int tid = threadIdx.x, lane = tid & 63, wid = tid >> 6;
  const int l31 = lane & 31, l5 = lane >> 5;
  const int qg = wid >> 1, tw = wid & 1;
  const int sqg = qb0 + qg * 64;

  // block-wide staging byte offsets (32-bit; saddr-form global_load_lds)
  const int stt = tid >> 3;
  const int sch = tid & 7;
  unsigned kboff[2], vboff[2];
#pragma unroll
  for (int r = 0; r < 2; ++r) {
    const int tt = r * 32 + stt;
    const int ch = sch ^ (tt & 7);
    kboff[r] = (unsigned)(tt * 1024 + nh * 64 + ch * 8) * 2u;
    vboff[r] = (unsigned)(nh * 262144 + tt * 4096 + ch * 8) * 2u;
  }

  // Q fragments (B-operand: col s, k=d), 2 col groups x 4 d-chunks
  short8_t qf[2][4];
#pragma unroll
  for (int cg = 0; cg < 2; ++cg)
#pragma unroll
    for (int kcd = 0; kcd < 4; ++kcd)
      qf[cg][kcd] = *(const short8_t*)(qo + (size_t)(sqg + cg * 32 + l31) * 1024 +
                                       nh * 64 + kcd * 16 + l5 * 8);

  // ones B-fragment for row-sum MFMA (col 0 = 1.0 across all k)
  union { unsigned int u[4]; short8_t v; } ou;
  {
    const unsigned int ov = (l31 == 0) ? 0x3F803F80u : 0u;
    ou.u[0] = ov; ou.u[1] = ov; ou.u[2] = ov; ou.u[3] = ov;
  }
  const short8_t ones = ou.v;

  // hoisted LDS byte offsets
  int kofl[4];
  {
    const int row = tw * 32 + l31;
#pragma unroll
    for (int kcd = 0; kcd < 4; ++kcd)
      kofl[kcd] = row * 128 + (((kcd * 2 + l5) ^ (row & 7)) * 16);
  }
  int vofl[2][2];
#pragma unroll
  for (int n = 0; n < 2; ++n) {
    const int row = n * 32 + l31;
#pragma unroll
    for (int kc = 0; kc < 2; ++kc)
      vofl[n][kc] = row * 128 + (((tw * 4 + kc * 2 + l5) ^ (row & 7)) * 16);
  }

  f32x16 zro;
#pragma unroll
  for (int r = 0; r < 16; ++r) zro[r] = 0.f;
  f32x16 aco00 = zro, aco01 = zro, aco10 = zro, aco11 = zro;  // [cg][n]
  f32x16 acl0 = zro, acl1 = zro;                              // row-sums

#define STAGEK(buf, kvb)                                                       \
  {                                                                            \
    const unsigned kk_ = (unsigned)(kvb) * 2048u;                              \
    _Pragma("unroll") for (int r = 0; r < 2; ++r)                              \
        gll16(koB + (kboff[r] + kk_),                                          \
              (char*)lKb + (buf) * 8192 + r * 4096 + wid * 1024);              \
  }
#define STAGEV(buf, kvb)                                                       \
  {                                                                            \
    const unsigned vv_ = (unsigned)(kvb) * 2u;                                 \
    _Pragma("unroll") for (int r = 0; r < 2; ++r)                              \
        gll16(vtB + (vboff[r] + vv_),                                          \
              (char*)lVb + (buf) * 8192 + r * 4096 + wid * 1024);              \
  }
// QK^T for tile idx from K buffer kb -> acs pair (zero-C first MFMA)
#define QKT(kb, a0, a1)                                                        \
  {                                                                            \
    const char* lKc_ = (const char*)lKb + (kb) * 8192;                         \
    short8_t kfr_[4];                                                          \
    _Pragma("unroll") for (int kcd = 0; kcd < 4; ++kcd)                        \
        kfr_[kcd] = *(const short8_t*)(lKc_ + kofl[kcd]);                      \
    a0 = MFMA32(kfr_[0], qf[0][0], zro);                                       \
    a1 = MFMA32(kfr_[0], qf[1][0], zro);                                       \
    _Pragma("unroll") for (int kcd = 1; kcd < 4; ++kcd) {                      \
      a0 = MFMA32(kfr_[kcd], qf[0][kcd], a0);                                  \
      a1 = MFMA32(kfr_[kcd], qf[1][kcd], a1);                                  \
    }                                                                          \
  }

  // prologue: K(0),V(0),K(1) staged; QK(0)
  STAGEK(0, 0);
  STAGEV(0, 0);
  STAGEK(1, 64);
  __syncthreads();
  f32x16 acs0, acs1;
  QKT(0, acs0, acs1);

  for (int i = 0; i < 63; ++i) {
    // stage K(i+2) into kbuf[i&1], V(i+1) into vbuf[(i+1)&1]
    if (i < 62) STAGEK(i & 1, (i + 2) << 6);
    STAGEV((i + 1) & 1, (i + 1) << 6);

    // QK(i+1) — matrix pipe, independent of S(i) processing
    f32x16 acsN0, acsN1;
    __builtin_amdgcn_s_setprio(1);
    QKT((i + 1) & 1, acsN0, acsN1);
    __builtin_amdgcn_s_setprio(0);

    // exp + pack S(i) — VALU/trans, overlaps QK(i+1) on matrix pipe
#pragma unroll
    for (int r = 0; r < 16; ++r) {
      acs0[r] = fexp2(acs0[r]);
      acs1[r] = fexp2(acs1[r]);
    }
    short8_t pa00, pa01, pa10, pa11;
    packP(acs0, pa00, pa01);
    packP(acs1, pa10, pa11);

    // PV(i) + row-sum MFMAs from vbuf[i&1]
    const char* lVc = (const char*)lVb + (i & 1) * 8192;
    const short8_t vf00 = *(const short8_t*)(lVc + vofl[0][0]);
    const short8_t vf10 = *(const short8_t*)(lVc + vofl[1][0]);
    const short8_t vf01 = *(const short8_t*)(lVc + vofl[0][1]);
    const short8_t vf11 = *(const short8_t*)(lVc + vofl[1][1]);
    __builtin_amdgcn_s_setprio(1);
    aco00 = MFMA32(pa00, vf00, aco00);
    aco10 = MFMA32(pa10, vf00, aco10);
    aco01 = MFMA32(pa00, vf10, aco01);
    aco11 = MFMA32(pa10, vf10, aco11);
    acl0 = MFMA32(pa00, ones, acl0);
    acl1 = MFMA32(pa10, ones, acl1);
    aco00 = MFMA32(pa01, vf01, aco00);
    aco10 = MFMA32(pa11, vf01, aco10);
    aco01 = MFMA32(pa01, vf11, aco01);
    aco11 = MFMA32(pa11, vf11, aco11);
    acl0 = MFMA32(pa01, ones, acl0);
    acl1 = MFMA32(pa11, ones, acl1);
    __builtin_amdgcn_s_setprio(0);

    __syncthreads();
    acs0 = acsN0;
    acs1 = acsN1;
  }

  // peeled i=63: exp/pack + PV from vbuf[1]
  {
#pragma unroll
    for (int r = 0; r < 16; ++r) {
      acs0[r] = fexp2(acs0[r]);
      acs1[r] = fexp2(acs1[r]);
    }
    short8_t pa00, pa01, pa10, pa11;
    packP(acs0, pa00, pa01);
    packP(acs1, pa10, pa11);
    const char* lVc = (const char*)lVb + 8192;
    const short8_t vf00 = *(const short8_t*)(lVc + vofl[0][0]);
    const short8_t vf10 = *(const short8_t*)(lVc + vofl[1][0]);
    const short8_t vf01 = *(const short8_t*)(lVc + vofl[0][1]);
    const short8_t vf11 = *(const short8_t*)(lVc + vofl[1][1]);
    aco00 = MFMA32(pa00, vf00, aco00);
    aco10 = MFMA32(pa10, vf00, aco10);
    aco01 = MFMA32(pa00, vf10, aco01);
    aco11 = MFMA32(pa10, vf10, aco11);
    acl0 = MFMA32(pa00, ones, acl0);
    acl1 = MFMA32(pa10, ones, acl1);
    aco00 = MFMA32(pa01, vf01, aco00);
    aco10 = MFMA32(pa11, vf01, aco10);
    aco01 = MFMA32(pa01, vf11, aco01);
    aco11 = MFMA32(pa11, vf11, aco11);
    acl0 = MFMA32(pa01, ones, acl0);
    acl1 = MFMA32(pa11, ones, acl1);
  }
  __syncthreads();  // smem reuse below aliases K/V buffers

  // two-pass epilogue over q-groups: transpose via padded LDS, normalize,
  // scramble, add residual. aco: lane=d col (n*32+l31), reg=s row.
#pragma unroll
  for (int p = 0; p < 2; ++p) {
    if (p) __syncthreads();
    if (qg == p) {
      float* myO = fO + tw * 4160;  // 64*65
#pragma unroll
      for (int r = 0; r < 16; ++r) {
        const int sl = (r & 3) + 8 * (r >> 2) + 4 * l5;
        myO[l31 * 65 + sl] = aco00[r];
        myO[(l31 + 32) * 65 + sl] = aco01[r];
        myO[l31 * 65 + 32 + sl] = aco10[r];
        myO[(l31 + 32) * 65 + 32 + sl] = aco11[r];
      }
      if (l31 == 0) {
#pragma unroll
        for (int r = 0; r < 16; ++r) {
          const int sl = (r & 3) + 8 * (r >> 2) + 4 * l5;
          fRs[tw * 64 + sl] = acl0[r];
          fRs[tw * 64 + 32 + sl] = acl1[r];
        }
      }
    }
    __syncthreads();
    {
      const int s = tid & 63;
      const int sg = qb0 + p * 64 + s;
      const float inv = 1.f / (fRs[s] + fRs[64 + s]);
      const int scol = sg & 1023, srow = sg >> 10;
#pragma unroll
      for (int i = 0; i < 16; ++i) {
        const int d = (tid >> 6) * 16 + i;
        const float v = fO[d * 65 + s] + fO[4160 + d * 65 + s];
        const int idx = (nh * 256 + d * 4 + srow) * 1024 + scol;
        out[idx] = qin[idx] + v * inv;
      }
    }
  }
#undef STAGEK
#undef STAGEV
#undef QKT
}

// ---------------------------------------------------------------------------
extern "C" void kernel_launch(void* const* d_in, const int* in_sizes, int n_in,
                              void* d_out, int out_size, void* d_ws,
                              size_t ws_size, hipStream_t stream) {
  const float* qin = (const float*)d_in[0];
  const float* kin = (const float*)d_in[1];
  const float* vin = (const float*)d_in[2];
  const float* wq = (const float*)d_in[3];
  const float* bq = (const float*)d_in[4];
  const float* wk = (const float*)d_in[5];
  const float* bk = (const float*)d_in[6];
  const float* wv = (const float*)d_in[7];
  const float* bv = (const float*)d_in[8];
  unsigned short* ws = (unsigned short*)d_ws;
  float* out = (float*)d_out;

  prep_convert<<<dim3(8192), dim3(256), 0, stream>>>(qin, kin, vin, wq, wk, wv, ws);
  qkv_gemm<<<dim3(8, 32, 3), dim3(256), 0, stream>>>(ws, bq, bk, bv);
  attn_fwd<<<dim3(32, 16), dim3(256), 0, stream>>>(ws, qin, out);
}

// Round 8
// 137.476 us; speedup vs baseline: 1.0030x; 1.0030x over previous
//
#include <hip/hip_runtime.h>
#include <stdint.h>

// ---------------------------------------------------------------------------
// MultiHeadAttention: B=1, S=4096, H=1024, NH=16, DH=64
//   q = relu(Q @ Wq^T + bq), k = ..., v = ...
//   per head: softmax(q k^T / 8) v,   output scrambled (torch-faithful
//   transpose(0,1,3,2).reshape) + queries.
// R8: occupancy play — 512-thread attn blocks (8 waves = 4 qg x 2 tw),
//     wave = 32q x 32t, regs <= 128 => 4 waves/SIMD (2x R7). Row-sums back
//     to VALU chains (reg economy). KVBLK=64, 32KB LDS, 1 gll16/thread/tile.
//     4-pass transpose epilogue. No software pipeline (R7 proved neutral).
// ---------------------------------------------------------------------------

#define SEQ 4096
#define HID 1024
#define NHEAD 16
#define DHEAD 64

typedef __attribute__((ext_vector_type(8))) short short8_t;     // 8 x bf16
typedef __attribute__((ext_vector_type(4))) float f32x4;        // 16x16 acc
typedef __attribute__((ext_vector_type(16))) float f32x16;      // 32x32 acc
typedef __attribute__((ext_vector_type(2))) unsigned int u32x2;

// ws layout (bf16 elements)
#define WS_QB   0u          // queries bf16 [4096][1024]
#define WS_KB   4194304u
#define WS_VB   8388608u
#define WS_WQ   12582912u   // weights bf16 [1024][1024] x3
#define WS_QO   15728640u   // q proj [4096][1024]
#define WS_KO   19922944u   // k proj (pre-scaled by (1/8)*log2e) [4096][1024]
#define WS_VT   24117248u   // v proj transposed [16][64][4096]

__device__ __forceinline__ unsigned short f2bf(float f) {
  union { float f; unsigned int u; } x; x.f = f;
  unsigned int u = x.u;
  return (unsigned short)((u + 0x7FFFu + ((u >> 16) & 1u)) >> 16);
}

// raw v_exp_f32 — valid: inputs are >= 0 (ReLU'd Q,K dot) and < ~16
__device__ __forceinline__ float fexp2(float x) {
#if __has_builtin(__builtin_amdgcn_exp2f)
  return __builtin_amdgcn_exp2f(x);
#else
  float r; asm("v_exp_f32 %0, %1" : "=v"(r) : "v"(x)); return r;
#endif
}

// packed f32x2 -> bf16x2 (lo = a, hi = b)
__device__ __forceinline__ unsigned int pk2(float a, float b) {
  unsigned int r;
  asm("v_cvt_pk_bf16_f32 %0, %1, %2" : "=v"(r) : "v"(a), "v"(b));
  return r;
}

// swap hi-32-lanes of a with lo-32-lanes of b
__device__ __forceinline__ void pl32swap(unsigned int& a, unsigned int& b) {
  asm("v_permlane32_swap_b32 %0, %1" : "+v"(a), "+v"(b));
}

__device__ __forceinline__ void gll16(const void* g, void* l) {
  __builtin_amdgcn_global_load_lds(
      (const __attribute__((address_space(1))) void*)g,
      (__attribute__((address_space(3))) void*)l, 16, 0, 0);
}

// P pack+redistribute: acs (S^T regs=t, lane=s col) -> two PV A-frags
__device__ __forceinline__ void packP(const f32x16& a, short8_t& p0,
                                      short8_t& p1) {
  unsigned int w0 = pk2(a[0], a[1]),   w1 = pk2(a[2], a[3]);
  unsigned int w2 = pk2(a[4], a[5]),   w3 = pk2(a[6], a[7]);
  unsigned int w4 = pk2(a[8], a[9]),   w5 = pk2(a[10], a[11]);
  unsigned int w6 = pk2(a[12], a[13]), w7 = pk2(a[14], a[15]);
  pl32swap(w0, w2);
  pl32swap(w1, w3);
  pl32swap(w4, w6);
  pl32swap(w5, w7);
  union { unsigned int u[4]; short8_t v; } q0, q1;
  q0.u[0] = w0; q0.u[1] = w1; q0.u[2] = w2; q0.u[3] = w3;
  q1.u[0] = w4; q1.u[1] = w5; q1.u[2] = w6; q1.u[3] = w7;
  p0 = q0.v; p1 = q1.v;
}

#define MFMA32(a, b, c) __builtin_amdgcn_mfma_f32_32x32x16_bf16(a, b, c, 0, 0, 0)

// ---------------------------------------------------------------------------
// Kernel 1: fp32 -> bf16 for 3 inputs (4M each) + 3 weights (1M each)
// ---------------------------------------------------------------------------
__global__ void __launch_bounds__(256) prep_convert(
    const float* __restrict__ qin, const float* __restrict__ kin,
    const float* __restrict__ vin, const float* __restrict__ wq,
    const float* __restrict__ wk, const float* __restrict__ wv,
    unsigned short* __restrict__ ws) {
  const int total = 3932160;  // (3*4194304 + 3*1048576) / 4
  for (int i = blockIdx.x * blockDim.x + threadIdx.x; i < total;
       i += gridDim.x * blockDim.x) {
    const float* src; unsigned short* dst; int off;
    if (i < 3145728) {
      int which = i >> 20;
      off = (i & 1048575) << 2;
      src = which == 0 ? qin : (which == 1 ? kin : vin);
      dst = ws + which * 4194304u;
    } else {
      int j = i - 3145728;
      int which = j >> 18;
      off = (j & 262143) << 2;
      src = which == 0 ? wq : (which == 1 ? wk : wv);
      dst = ws + WS_WQ + which * 1048576u;
    }
    float4 f = *(const float4*)(src + off);
    u32x2 p;
    p.x = f2bf(f.x) | ((unsigned int)f2bf(f.y) << 16);
    p.y = f2bf(f.z) | ((unsigned int)f2bf(f.w) << 16);
    *(u32x2*)(dst + off) = p;
  }
}

// ---------------------------------------------------------------------------
// Kernel 2: bf16 GEMM  C[4096,1024] = relu(X @ W^T + b), z selects Q/K/V.
// z==1 (K) output pre-scaled by (1/8)*log2e; z==2 writes vt[nh][d][t].
// XCD-aware block swizzle: each XCD takes 4 bm rows x all 8 bn.
// ---------------------------------------------------------------------------
__global__ void __launch_bounds__(256) qkv_gemm(
    unsigned short* __restrict__ ws, const float* __restrict__ bq,
    const float* __restrict__ bk, const float* __restrict__ bv) {
  __shared__ alignas(16) unsigned short lA[128 * 32];
  __shared__ alignas(16) unsigned short lB[128 * 32];
  const int z = blockIdx.z;
  const unsigned short* A = ws + z * 4194304u;
  const unsigned short* W = ws + WS_WQ + z * 1048576u;
  const float* bias = z == 0 ? bq : (z == 1 ? bk : bv);
  const int tid = threadIdx.x;
  const int lane = tid & 63;
  const int wid = tid >> 6;
  const int wr = wid >> 1, wc = wid & 1;
  const int lin = blockIdx.y * 8 + blockIdx.x;         // 0..255
  const int nid = (lin & 7) * 32 + (lin >> 3);
  const int bm = nid >> 3, bn = nid & 7;
  const int l15 = lane & 15, l4 = lane >> 4;

  f32x4 acc[4][4];
#pragma unroll
  for (int m = 0; m < 4; ++m)
#pragma unroll
    for (int n = 0; n < 4; ++n) acc[m][n] = {0.f, 0.f, 0.f, 0.f};

  const int srow = lane >> 2;
  const int scs = lane & 3;

  for (int kt = 0; kt < 1024; kt += 32) {
    __syncthreads();
#pragma unroll
    for (int c = 0; c < 2; ++c) {
      const int row = c * 64 + wid * 16 + srow;
      const int ch = scs ^ ((row >> 1) & 3);
      gll16(A + (size_t)(bm * 128 + row) * 1024 + kt + ch * 8,
            (char*)lA + c * 4096 + wid * 1024);
      gll16(W + (size_t)(bn * 128 + row) * 1024 + kt + ch * 8,
            (char*)lB + c * 4096 + wid * 1024);
    }
    __syncthreads();
    short8_t af[4], bf[4];
#pragma unroll
    for (int m = 0; m < 4; ++m) {
      const int row = wr * 64 + m * 16 + l15;
      const int ch = l4 ^ ((row >> 1) & 3);
      af[m] = *(const short8_t*)(lA + row * 32 + ch * 8);
    }
#pragma unroll
    for (int n = 0; n < 4; ++n) {
      const int row = wc * 64 + n * 16 + l15;
      const int ch = l4 ^ ((row >> 1) & 3);
      bf[n] = *(const short8_t*)(lB + row * 32 + ch * 8);
    }
#pragma unroll
    for (int m = 0; m < 4; ++m)
#pragma unroll
      for (int n = 0; n < 4; ++n)
        acc[m][n] = __builtin_amdgcn_mfma_f32_16x16x32_bf16(af[m], bf[n],
                                                            acc[m][n], 0, 0, 0);
  }

  const int row0 = bm * 128 + wr * 64;
  const int col0 = bn * 128 + wc * 64;
  if (z < 2) {
    const float scl = (z == 1) ? 0.18033688011112042f : 1.0f;  // (1/8)*log2e
    unsigned short* o = ws + WS_QO + z * 4194304u;
#pragma unroll
    for (int n = 0; n < 4; ++n) {
      const int col = col0 + n * 16 + l15;
      const float bb = bias[col];
#pragma unroll
      for (int m = 0; m < 4; ++m)
#pragma unroll
        for (int j = 0; j < 4; ++j) {
          const int row = row0 + m * 16 + l4 * 4 + j;
          o[(size_t)row * 1024 + col] = f2bf(fmaxf(acc[m][n][j] + bb, 0.f) * scl);
        }
    }
  } else {
    unsigned short* vt = ws + WS_VT;
#pragma unroll
    for (int n = 0; n < 4; ++n) {
      const int col = col0 + n * 16 + l15;
      const float bb = bias[col];
      const int nh = col >> 6, d = col & 63;
#pragma unroll
      for (int m = 0; m < 4; ++m) {
        const int t0 = row0 + m * 16 + l4 * 4;
        u32x2 p;
        p.x = f2bf(fmaxf(acc[m][n][0] + bb, 0.f)) |
              ((unsigned int)f2bf(fmaxf(acc[m][n][1] + bb, 0.f)) << 16);
        p.y = f2bf(fmaxf(acc[m][n][2] + bb, 0.f)) |
              ((unsigned int)f2bf(fmaxf(acc[m][n][3] + bb, 0.f)) << 16);
        *(u32x2*)(vt + (size_t)nh * 262144 + (size_t)d * 4096 + t0) = p;
      }
    }
  }
}

// ---------------------------------------------------------------------------
// Kernel 3: flash attention, 32x32x16 MFMA, 512-thread blocks.
// 8 waves = (qg 0..3) x (tw 0..1); wave = 32 q x 32 t. KVBLK = 64.
// S^T = mfma(K, Q^T); exp via raw v_exp_f32; row-sums via VALU chains;
// P in-register (cvt_pk + permlane32_swap). 4-pass transpose epilogue.
// ---------------------------------------------------------------------------
__global__ void __launch_bounds__(512, 4) attn_fwd(
    const unsigned short* __restrict__ ws, const float* __restrict__ qin,
    float* __restrict__ out) {
  // main: lK[2][64*64] 0..16KB, lV[2][64*64] 16..32KB (bf16)
  // epilogue overlay: fO[2][64][33] f32 (16896B) + fRs[2][32] (256B)
  __shared__ alignas(16) char smem[32768];
  const char* lKb = smem;
  const char* lVb = smem + 16384;
  float* fO = (float*)smem;                 // [2][64*33]
  float* fRs = (float*)(smem + 16896);      // [2][32]

  const unsigned short* qo = ws + WS_QO;
  const char* koB = (const char*)(ws + WS_KO);
  const char* vtB = (const char*)(ws + WS_VT);
  const int nh = blockIdx.y;
  const int qb0 = blockIdx.x * 128;
  const int tid = threadIdx.x, lane = tid & 63, wid = tid >> 6;  // wid 0..7
  const int l31 = lane & 31, l5 = lane >> 5;
  const int qg = wid >> 1, tw = wid & 1;
  const int sq = qb0 + qg * 32 + l31;  // this lane's q column

  // staging: 512 threads x one 16B chunk for K and V tiles (64 rows x 8 chunks)
  const int stt = tid >> 3;   // 0..63 row (t for K, d for V)
  const int sch = tid & 7;    // chunk slot
  const unsigned kgoff =
      (unsigned)(stt * 1024 + nh * 64 + ((sch ^ (stt & 7)) * 8)) * 2u;
  const unsigned vgoff =
      (unsigned)(nh * 262144 + stt * 4096 + ((sch ^ (stt & 7)) * 8)) * 2u;
  const unsigned ldst = (unsigned)tid * 16u;

  // Q fragments (B-operand: col s=l31, k=d), 4 d-chunks
  short8_t qf[4];
#pragma unroll
  for (int kcd = 0; kcd < 4; ++kcd)
    qf[kcd] = *(const short8_t*)(qo + (size_t)sq * 1024 + nh * 64 +
                                 kcd * 16 + l5 * 8);

  // hoisted LDS read offsets
  int kofl[4];
  {
    const int row = tw * 32 + l31;
#pragma unroll
    for (int kcd = 0; kcd < 4; ++kcd)
      kofl[kcd] = row * 128 + (((kcd * 2 + l5) ^ (row & 7)) * 16);
  }
  int vofl[2][2];
#pragma unroll
  for (int n = 0; n < 2; ++n) {
    const int row = n * 32 + l31;
#pragma unroll
    for (int kc = 0; kc < 2; ++kc)
      vofl[n][kc] = row * 128 + (((tw * 4 + kc * 2 + l5) ^ (row & 7)) * 16);
  }

  f32x16 zro;
#pragma unroll
  for (int r = 0; r < 16; ++r) zro[r] = 0.f;
  f32x16 aco0 = zro, aco1 = zro;  // O partial [n=d-half]
  float rs0 = 0.f, rs1 = 0.f, rs2 = 0.f, rs3 = 0.f;

#define STAGE(buf, kvb)                                                        \
  {                                                                            \
    gll16(koB + (kgoff + (unsigned)(kvb) * 2048u),                             \
          (char*)lKb + (buf) * 8192 + ldst);                                   \
    gll16(vtB + (vgoff + (unsigned)(kvb) * 2u),                                \
          (char*)lVb + (buf) * 8192 + ldst);                                   \
  }

  STAGE(0, 0);
  __syncthreads();
  int cur = 0;

  for (int kv = 0; kv < 4096; kv += 64) {
    if (kv + 64 < 4096) STAGE(cur ^ 1, kv + 64);
    const char* lKc = lKb + cur * 8192;
    const char* lVc = lVb + cur * 8192;

    // S^T[t][s] = sum_d K[t][d] Q[s][d]  (K pre-scaled by (1/8)*log2e)
    __builtin_amdgcn_s_setprio(1);
    f32x16 acs = MFMA32(*(const short8_t*)(lKc + kofl[0]), qf[0], zro);
#pragma unroll
    for (int kcd = 1; kcd < 4; ++kcd)
      acs = MFMA32(*(const short8_t*)(lKc + kofl[kcd]), qf[kcd], acs);
    __builtin_amdgcn_s_setprio(0);

    // P = exp2(S); row-sums in 4 chains
#pragma unroll
    for (int r = 0; r < 16; r += 4) {
      const float p0 = fexp2(acs[r]);
      const float p1 = fexp2(acs[r + 1]);
      const float p2 = fexp2(acs[r + 2]);
      const float p3 = fexp2(acs[r + 3]);
      acs[r] = p0; acs[r + 1] = p1; acs[r + 2] = p2; acs[r + 3] = p3;
      rs0 += p0; rs1 += p1; rs2 += p2; rs3 += p3;
    }

    short8_t pa0, pa1;
    packP(acs, pa0, pa1);

    // PV: O[s][d] += sum_t P[s][t] V[t][d]
    const short8_t vf00 = *(const short8_t*)(lVc + vofl[0][0]);
    const short8_t vf10 = *(const short8_t*)(lVc + vofl[1][0]);
    const short8_t vf01 = *(const short8_t*)(lVc + vofl[0][1]);
    const short8_t vf11 = *(const short8_t*)(lVc + vofl[1][1]);
    __builtin_amdgcn_s_setprio(1);
    aco0 = MFMA32(pa0, vf00, aco0);
    aco1 = MFMA32(pa0, vf10, aco1);
    aco0 = MFMA32(pa1, vf01, aco0);
    aco1 = MFMA32(pa1, vf11, aco1);
    __builtin_amdgcn_s_setprio(0);

    __syncthreads();
    cur ^= 1;
  }

  // complete row-sum: chains + cross-t-half (l5)
  float rs = (rs0 + rs1) + (rs2 + rs3);
  rs += __shfl_xor(rs, 32);

  // 4-pass epilogue over q-groups: transpose via padded LDS overlay,
  // combine tw halves, normalize, scramble, add residual.
#pragma unroll 1
  for (int p = 0; p < 4; ++p) {
    if (qg == p) {
      float* myO = fO + tw * 2112;  // 64*33
#pragma unroll
      for (int r = 0; r < 16; ++r) {
        const int sl = (r & 3) + 8 * (r >> 2) + 4 * l5;
        myO[l31 * 33 + sl] = aco0[r];
        myO[(l31 + 32) * 33 + sl] = aco1[r];
      }
      if (l5 == 0) fRs[tw * 32 + l31] = rs;
    }
    __syncthreads();
    {
      const int s = tid & 31;
      const int dg = tid >> 5;  // 0..15
      const int sg = qb0 + p * 32 + s;
      const float inv = 1.f / (fRs[s] + fRs[32 + s]);
      const int scol = sg & 1023, srow = sg >> 10;
#pragma unroll
      for (int i = 0; i < 4; ++i) {
        const int d = dg * 4 + i;
        const float v = fO[d * 33 + s] + fO[2112 + d * 33 + s];
        const int idx = (nh * 256 + d * 4 + srow) * 1024 + scol;
        out[idx] = qin[idx] + v * inv;
      }
    }
    __syncthreads();
  }
#undef STAGE
}

// ---------------------------------------------------------------------------
extern "C" void kernel_launch(void* const* d_in, const int* in_sizes, int n_in,
                              void* d_out, int out_size, void* d_ws,
                              size_t ws_size, hipStream_t stream) {
  const float* qin = (const float*)d_in[0];
  const float* kin = (const float*)d_in[1];
  const float* vin = (const float*)d_in[2];
  const float* wq = (const float*)d_in[3];
  const float* bq = (const float*)d_in[4];
  const float* wk = (const float*)d_in[5];
  const float* bk = (const float*)d_in[6];
  const float* wv = (const float*)d_in[7];
  const float* bv = (const float*)d_in[8];
  unsigned short* ws = (unsigned short*)d_ws;
  float* out = (float*)d_out;

  prep_convert<<<dim3(8192), dim3(256), 0, stream>>>(qin, kin, vin, wq, wk, wv, ws);
  qkv_gemm<<<dim3(8, 32, 3), dim3(256), 0, stream>>>(ws, bq, bk, bv);
  attn_fwd<<<dim3(32, 16), dim3(512), 0, stream>>>(ws, qin, out);
}